// Round 1
// 2425.436 us; speedup vs baseline: 1.0726x; 1.0726x over previous
//
#include <hip/hip_runtime.h>

typedef unsigned short u16;

#define BB 64
#define TT 512
#define DD 512
#define VV 50257
#define NCAND 509
#define NFWD 48
#define NRETRO 16

__device__ __forceinline__ float bf2f(u16 u) {
  union { unsigned int i; float f; } v;
  v.i = ((unsigned int)u) << 16;
  return v.f;
}
__device__ __forceinline__ u16 f2bf(float f) {
  union { float f; unsigned int u; } v; v.f = f;
  unsigned int u = v.u;
  u += 0x7fffu + ((u >> 16) & 1u);   // RNE
  return (u16)(u >> 16);
}
__device__ __forceinline__ float ldsel(const void* p, size_t i, int isbf) {
  return isbf ? bf2f(((const u16*)p)[i]) : ((const float*)p)[i];
}

// dtype detector (bf16-packed vs fp32) on first 16 words of embed
__global__ void detect_k(const unsigned int* __restrict__ w, int* __restrict__ flag) {
  int bf = 1;
  for (int i = 0; i < 16; ++i) {
    unsigned int b1 = (w[i] >> 8) & 0x7fu;
    if (!(b1 >= 0x30u && b1 < 0x40u)) bf = 0;
  }
  *flag = bf;
}

// sentinel: encodes ws_size into the output so absmax error reports it
__global__ void sentinel_k(float* __restrict__ out, int n, float val) {
  int i = blockIdx.x * 256 + threadIdx.x;
  if (i < n) out[i] = val;
}

// ---------------------------------------------------------------------------
// Tiled GEMM: C[M,N] = epilogue(A[M,K] @ B[K,N])
//  AG: A gathered from input table (gbase, gidx) | ADDM=1: +input rows via
//  adg_idx | ADDM=2: +fp32 addf[(m>>add_shift)*addf_ld+n] | RELU | ACC: +=C_old
//  OUTBF: store bf16 | boff: element offset into B | bias_eoff: elem offset
// ---------------------------------------------------------------------------
template<int AG, int ADDM, int RELU, int ACC, int OUTBF>
__global__ __launch_bounds__(256) void gemm_k(
    const float* __restrict__ A, int lda,
    const void* __restrict__ gbase, const int* __restrict__ gidx,
    const void* __restrict__ Bw, int ldb, size_t boff,
    const void* __restrict__ bias, size_t bias_eoff,
    const void* __restrict__ adg_base, const int* __restrict__ adg_idx, int adg_ld,
    const float* __restrict__ addf, int add_shift, int addf_ld,
    void* __restrict__ Cv, int ldc, int K,
    const int* __restrict__ flagp)
{
  __shared__ float As[16][68];
  __shared__ float Bs[16][68];
  int isbf = *flagp;
  int tid = threadIdx.x;
  int m0 = blockIdx.y * 64;
  int n0 = blockIdx.x * 64;
  int tx = tid & 15, ty = tid >> 4;
  int arow = tid >> 2;
  int akq  = (tid & 3) << 2;
  int bcol = tid & 63;
  int bk0  = tid >> 6;

  size_t a_off;
  if (AG) a_off = (size_t)gidx[m0 + arow] * (size_t)lda;
  else    a_off = (size_t)(m0 + arow) * (size_t)lda;

  float acc[4][4] = {};

  for (int k0 = 0; k0 < K; k0 += 16) {
    if (AG) {
      if (isbf) {
        const u16* p = (const u16*)gbase + a_off + k0 + akq;
        As[akq + 0][arow] = bf2f(p[0]);
        As[akq + 1][arow] = bf2f(p[1]);
        As[akq + 2][arow] = bf2f(p[2]);
        As[akq + 3][arow] = bf2f(p[3]);
      } else {
        float4 v = *(const float4*)((const float*)gbase + a_off + k0 + akq);
        As[akq + 0][arow] = v.x;
        As[akq + 1][arow] = v.y;
        As[akq + 2][arow] = v.z;
        As[akq + 3][arow] = v.w;
      }
    } else {
      float4 v = *(const float4*)(A + a_off + k0 + akq);
      As[akq + 0][arow] = v.x;
      As[akq + 1][arow] = v.y;
      As[akq + 2][arow] = v.z;
      As[akq + 3][arow] = v.w;
    }
    if (isbf) {
      const u16* bp = (const u16*)Bw + boff;
#pragma unroll
      for (int l = 0; l < 4; ++l) {
        int kb = bk0 + (l << 2);
        Bs[kb][bcol] = bf2f(bp[(size_t)(k0 + kb) * ldb + n0 + bcol]);
      }
    } else {
      const float* bp = (const float*)Bw + boff;
#pragma unroll
      for (int l = 0; l < 4; ++l) {
        int kb = bk0 + (l << 2);
        Bs[kb][bcol] = bp[(size_t)(k0 + kb) * ldb + n0 + bcol];
      }
    }
    __syncthreads();
#pragma unroll
    for (int k = 0; k < 16; ++k) {
      float4 a4 = *(const float4*)&As[k][ty << 2];
      float4 b4 = *(const float4*)&Bs[k][tx << 2];
      float a[4] = {a4.x, a4.y, a4.z, a4.w};
      float bv[4] = {b4.x, b4.y, b4.z, b4.w};
#pragma unroll
      for (int i = 0; i < 4; ++i)
#pragma unroll
        for (int j = 0; j < 4; ++j) acc[i][j] += a[i] * bv[j];
    }
    __syncthreads();
  }

  int mrow = m0 + (ty << 2);
  int ncol = n0 + (tx << 2);
  float bi4[4] = {0.f, 0.f, 0.f, 0.f};
  if (bias) {
#pragma unroll
    for (int j = 0; j < 4; ++j) bi4[j] = ldsel(bias, bias_eoff + ncol + j, isbf);
  }
#pragma unroll
  for (int i = 0; i < 4; ++i) {
    int m = mrow + i;
    float v[4];
#pragma unroll
    for (int j = 0; j < 4; ++j) v[j] = acc[i][j] + bi4[j];
    if (ADDM == 1) {
      size_t base = (size_t)adg_idx[m] * adg_ld + ncol;
#pragma unroll
      for (int j = 0; j < 4; ++j) v[j] += ldsel(adg_base, base + j, isbf);
    }
    if (ADDM == 2) {
      const float* p = addf + (size_t)(m >> add_shift) * addf_ld + ncol;
#pragma unroll
      for (int j = 0; j < 4; ++j) v[j] += p[j];
    }
    if (ACC) {
      const float* cf = (const float*)Cv + (size_t)m * ldc + ncol;
#pragma unroll
      for (int j = 0; j < 4; ++j) v[j] += cf[j];
    }
    if (RELU) {
#pragma unroll
      for (int j = 0; j < 4; ++j) v[j] = fmaxf(v[j], 0.f);
    }
    if (OUTBF) {
      u16* cp = (u16*)Cv + (size_t)m * ldc + ncol;
#pragma unroll
      for (int j = 0; j < 4; ++j) cp[j] = f2bf(v[j]);
    } else {
      float4 o; o.x = v[0]; o.y = v[1]; o.z = v[2]; o.w = v[3];
      *(float4*)((float*)Cv + (size_t)m * ldc + ncol) = o;
    }
  }
}

__global__ __launch_bounds__(256) void ln_k(float* __restrict__ x,
                                            const void* __restrict__ g,
                                            const void* __restrict__ bt,
                                            const int* __restrict__ flagp) {
  int isbf = *flagp;
  float* p = x + (size_t)blockIdx.x * 512;
  int tid = threadIdx.x;
  __shared__ float red[256];
  __shared__ float stat[2];
  float v0 = p[tid], v1 = p[tid + 256];
  red[tid] = v0 + v1;
  __syncthreads();
  for (int s = 128; s > 0; s >>= 1) { if (tid < s) red[tid] += red[tid + s]; __syncthreads(); }
  if (tid == 0) stat[0] = red[0] * (1.0f / 512.0f);
  __syncthreads();
  float mu = stat[0];
  float d0 = v0 - mu, d1 = v1 - mu;
  red[tid] = d0 * d0 + d1 * d1;
  __syncthreads();
  for (int s = 128; s > 0; s >>= 1) { if (tid < s) red[tid] += red[tid + s]; __syncthreads(); }
  if (tid == 0) stat[1] = 1.0f / sqrtf(red[0] * (1.0f / 512.0f) + 1e-5f);
  __syncthreads();
  float inv = stat[1];
  p[tid]       = d0 * inv * ldsel(g, tid, isbf)       + ldsel(bt, tid, isbf);
  p[tid + 256] = d1 * inv * ldsel(g, tid + 256, isbf) + ldsel(bt, tid + 256, isbf);
}

template<int SIG>
__global__ __launch_bounds__(256) void score_k(const float* __restrict__ h,
                                               const void* __restrict__ w,
                                               const void* __restrict__ b,
                                               float* __restrict__ out,
                                               const int* __restrict__ flagp) {
  int isbf = *flagp;
  int bb = blockIdx.y; int t0 = blockIdx.x * 64;
  __shared__ float wl[512];
  for (int d = threadIdx.x; d < 512; d += 256) wl[d] = ldsel(w, d, isbf);
  __syncthreads();
  int wave = threadIdx.x >> 6, lane = threadIdx.x & 63;
  float bias = ldsel(b, 0, isbf);
  for (int r = wave; r < 64; r += 4) {
    const float* hp = h + ((size_t)bb * 512 + t0 + r) * 512;
    float s = 0.f;
#pragma unroll
    for (int d = 0; d < 8; ++d) s += hp[lane + d * 64] * wl[lane + d * 64];
#pragma unroll
    for (int off = 32; off > 0; off >>= 1) s += __shfl_xor(s, off);
    if (lane == 0) {
      float v = s + bias;
      if (SIG) v = 1.0f / (1.0f + expf(-v));
      out[bb * 512 + t0 + r] = v;
    }
  }
}

__global__ __launch_bounds__(256) void topk_fwd_k(const float* __restrict__ scores,
                                                  int* __restrict__ fwd_idx,
                                                  int* __restrict__ fwd_mask) {
  int b = blockIdx.x, tid = threadIdx.x;
  __shared__ float vals[512];
  __shared__ float rv[256];
  __shared__ int   ri[256];
  __shared__ int   selb[NFWD];
  for (int t = tid; t < 512; t += 256) {
    vals[t] = (t < NCAND) ? scores[b * 512 + t] : -3.0e38f;
    fwd_mask[b * 512 + t] = 0;
  }
  __syncthreads();
  for (int it = 0; it < NFWD; ++it) {
    float bv = -3.0e38f; int bi = 0x7fffffff;
    for (int t = tid; t < 512; t += 256) {
      float v = vals[t];
      if (v > bv || (v == bv && t < bi)) { bv = v; bi = t; }
    }
    rv[tid] = bv; ri[tid] = bi;
    __syncthreads();
    for (int s = 128; s > 0; s >>= 1) {
      if (tid < s) {
        float ov = rv[tid + s]; int oi = ri[tid + s];
        if (ov > rv[tid] || (ov == rv[tid] && oi < ri[tid])) { rv[tid] = ov; ri[tid] = oi; }
      }
      __syncthreads();
    }
    if (tid == 0) { selb[it] = ri[0]; vals[ri[0]] = -3.0e38f; }
    __syncthreads();
  }
  if (tid == 0) {
    for (int i = 1; i < NFWD; ++i) {
      int v = selb[i], j = i - 1;
      while (j >= 0 && selb[j] > v) { selb[j + 1] = selb[j]; --j; }
      selb[j + 1] = v;
    }
    for (int i = 0; i < NFWD; ++i) {
      fwd_idx[b * NFWD + i] = selb[i];
      fwd_mask[b * 512 + selb[i]] = 1;
    }
  }
}

__global__ __launch_bounds__(256) void topk_retro_k(const float* __restrict__ gs,
                                                    const int* __restrict__ fwd_mask,
                                                    int* __restrict__ sel) {
  int b = blockIdx.x, tid = threadIdx.x;
  __shared__ float vals[512];
  __shared__ float rv[256];
  __shared__ int   ri[256];
  for (int t = tid; t < 512; t += 256) {
    float v;
    if (t < NCAND) v = fwd_mask[b * 512 + t] ? -1.0e9f : gs[b * 512 + t];
    else v = -3.0e38f;
    vals[t] = v;
  }
  __syncthreads();
  for (int it = 0; it < NRETRO; ++it) {
    float bv = -3.0e38f; int bi = 0x7fffffff;
    for (int t = tid; t < 512; t += 256) {
      float v = vals[t];
      if (v > bv || (v == bv && t < bi)) { bv = v; bi = t; }
    }
    rv[tid] = bv; ri[tid] = bi;
    __syncthreads();
    for (int s = 128; s > 0; s >>= 1) {
      if (tid < s) {
        float ov = rv[tid + s]; int oi = ri[tid + s];
        if (ov > rv[tid] || (ov == rv[tid] && oi < ri[tid])) { rv[tid] = ov; ri[tid] = oi; }
      }
      __syncthreads();
    }
    if (tid == 0) { sel[b * NRETRO + it] = ri[0]; vals[ri[0]] = -3.0e38f; }
    __syncthreads();
  }
}

// context mean, two-stage: 512 partial blocks (4 waves/SIMD) then tiny reduce.
// Old single-stage version ran 64 blocks (0.5 waves/SIMD) streaming 64MB
// latency-bound.
__global__ __launch_bounds__(512) void context_part_k(const float* __restrict__ h,
                                                      float* __restrict__ part) {
  int b = blockIdx.x >> 3, c = blockIdx.x & 7, d = threadIdx.x;
  const float* hp = h + ((size_t)b * 512 + c * 64) * 512 + d;
  float s = 0.f;
#pragma unroll 8
  for (int t = 0; t < 64; ++t) s += hp[(size_t)t * 512];
  part[(size_t)((b << 3) + c) * 512 + d] = s;
}
__global__ __launch_bounds__(512) void context_red_k(const float* __restrict__ part,
                                                     float* __restrict__ ctx) {
  int b = blockIdx.x, d = threadIdx.x;
  float s = 0.f;
#pragma unroll
  for (int c = 0; c < 8; ++c) s += part[(size_t)((b << 3) + c) * 512 + d];
  ctx[b * 512 + d] = s * (1.0f / 512.0f);
}

__global__ __launch_bounds__(256) void fwdh_gather_k(const float* __restrict__ h,
                                                     const int* __restrict__ fwd_idx,
                                                     float* __restrict__ fwd_h) {
  int idx = blockIdx.x * 256 + threadIdx.x;
  int d = idx & 511, r = idx >> 9, b = r / NFWD, i = r % NFWD;
  int t = fwd_idx[b * NFWD + i];
  fwd_h[idx] = h[((size_t)b * 512 + t) * 512 + d];
}
__global__ __launch_bounds__(256) void retro_gather_k(const float* __restrict__ h,
                                                      const int* __restrict__ sel,
                                                      float* __restrict__ mem) {
  int idx = blockIdx.x * 256 + threadIdx.x;
  int d = idx & 511, r = idx >> 9, b = r >> 4, j = r & 15;
  int t = sel[b * NRETRO + j];
  mem[((size_t)b * 64 + NFWD + j) * 512 + d] = h[((size_t)b * 512 + t) * 512 + d];
}
__global__ __launch_bounds__(256) void copy_re_k(const float* __restrict__ re,
                                                 float* __restrict__ mem) {
  int idx = blockIdx.x * 256 + threadIdx.x;
  int d = idx & 511, r = idx >> 9, b = r / NFWD, k = r % NFWD;
  mem[((size_t)b * 64 + k) * 512 + d] = re[idx];
}

// S[b,k,t] = q·k / sqrt(512); kk stored bf16
__global__ __launch_bounds__(256) void s_k(const float* __restrict__ q,
                                           const u16* __restrict__ kk,
                                           float* __restrict__ S) {
  int b = blockIdx.y, t0 = blockIdx.x * 64;
  int tid = threadIdx.x, tq = tid & 15, kq = tid >> 4;
  __shared__ float qs[16][49];
  __shared__ float ks[16][68];
  float acc[3][4] = {};
  for (int dc = 0; dc < 512; dc += 16) {
    for (int e = tid; e < 768; e += 256) {
      int d = e / 48, k2 = e % 48;
      qs[d][k2] = q[((size_t)b * 48 + k2) * 512 + dc + d];
    }
    for (int e = tid; e < 1024; e += 256) {
      int t = e >> 4, d = e & 15;
      ks[d][t] = bf2f(kk[((size_t)b * 512 + t0 + t) * 512 + dc + d]);
    }
    __syncthreads();
#pragma unroll
    for (int d = 0; d < 16; ++d) {
      float4 kv = *(const float4*)&ks[d][tq << 2];
#pragma unroll
      for (int j = 0; j < 3; ++j) {
        float qv = qs[d][kq * 3 + j];
        acc[j][0] += qv * kv.x; acc[j][1] += qv * kv.y;
        acc[j][2] += qv * kv.z; acc[j][3] += qv * kv.w;
      }
    }
    __syncthreads();
  }
  const float sc = 0.044194173824159216f;
#pragma unroll
  for (int j = 0; j < 3; ++j) {
    int k = kq * 3 + j;
    float4 o; o.x = acc[j][0] * sc; o.y = acc[j][1] * sc;
    o.z = acc[j][2] * sc; o.w = acc[j][3] * sc;
    *(float4*)&S[((size_t)b * 48 + k) * 512 + t0 + (tq << 2)] = o;
  }
}

__global__ __launch_bounds__(256) void softmax_k(float* __restrict__ S) {
  float* p = S + (size_t)blockIdx.x * 512;
  int tid = threadIdx.x;
  __shared__ float red[256];
  __shared__ float stat[2];
  float v0 = p[tid], v1 = p[tid + 256];
  red[tid] = fmaxf(v0, v1);
  __syncthreads();
  for (int s = 128; s > 0; s >>= 1) { if (tid < s) red[tid] = fmaxf(red[tid], red[tid + s]); __syncthreads(); }
  if (tid == 0) stat[0] = red[0];
  __syncthreads();
  float mx = stat[0];
  float e0 = expf(v0 - mx), e1 = expf(v1 - mx);
  red[tid] = e0 + e1;
  __syncthreads();
  for (int s = 128; s > 0; s >>= 1) { if (tid < s) red[tid] += red[tid + s]; __syncthreads(); }
  if (tid == 0) stat[1] = 1.0f / red[0];
  __syncthreads();
  float inv = stat[1];
  p[tid] = e0 * inv; p[tid + 256] = e1 * inv;
}

// attn_out[b,k,d] = sum_t P*v; vv stored bf16
__global__ __launch_bounds__(256) void pv_k(const float* __restrict__ P,
                                            const u16* __restrict__ vvp,
                                            float* __restrict__ ao) {
  int b = blockIdx.y, d0 = blockIdx.x * 64;
  int tid = threadIdx.x, dq = tid & 15, kq = tid >> 4;
  __shared__ float ps[16][49];
  __shared__ float vs[16][68];
  float acc[3][4] = {};
  for (int tc = 0; tc < 512; tc += 16) {
    for (int e = tid; e < 768; e += 256) {
      int t = e / 48, k2 = e % 48;
      ps[t][k2] = P[((size_t)b * 48 + k2) * 512 + tc + t];
    }
    for (int e = tid; e < 1024; e += 256) {
      int t = e >> 6, d = e & 63;
      vs[t][d] = bf2f(vvp[((size_t)b * 512 + tc + t) * 512 + d0 + d]);
    }
    __syncthreads();
#pragma unroll
    for (int t = 0; t < 16; ++t) {
      float4 vval = *(const float4*)&vs[t][dq << 2];
#pragma unroll
      for (int j = 0; j < 3; ++j) {
        float pp = ps[t][kq * 3 + j];
        acc[j][0] += pp * vval.x; acc[j][1] += pp * vval.y;
        acc[j][2] += pp * vval.z; acc[j][3] += pp * vval.w;
      }
    }
    __syncthreads();
  }
#pragma unroll
  for (int j = 0; j < 3; ++j) {
    int k = kq * 3 + j;
    float4 o; o.x = acc[j][0]; o.y = acc[j][1]; o.z = acc[j][2]; o.w = acc[j][3];
    *(float4*)&ao[((size_t)b * 48 + k) * 512 + d0 + (dq << 2)] = o;
  }
}

__global__ __launch_bounds__(512) void qh_k(const float* __restrict__ h,
                                            const void* __restrict__ rq_w,
                                            const void* __restrict__ rq_b,
                                            float* __restrict__ qh,
                                            const int* __restrict__ flagp) {
  int isbf = *flagp;
  int b = blockIdx.x, d = threadIdx.x;
  __shared__ float hr[512];
  hr[d] = h[((size_t)b * 512 + 510) * 512 + d];
  __syncthreads();
  float s = 0.f;
  if (isbf) {
    const u16* wp = (const u16*)rq_w;
    for (int k = 0; k < 512; ++k) s += hr[k] * bf2f(wp[(size_t)k * 512 + d]);
  } else {
    const float* wp = (const float*)rq_w;
    for (int k = 0; k < 512; ++k) s += hr[k] * wp[(size_t)k * 512 + d];
  }
  qh[b * 512 + d] = s + ldsel(rq_b, d, isbf);
}

// mem softmax + ctx; also emits ctxT[k][b] (transposed copy) so the vocab
// GEMM can read ctx through wave-uniform (scalar) loads.
__global__ __launch_bounds__(512) void mem_attn_k(const float* __restrict__ mem,
                                                  const float* __restrict__ qh,
                                                  float* __restrict__ ctx,
                                                  float* __restrict__ ctxT) {
  int b = blockIdx.x, tid = threadIdx.x;
  __shared__ float qv[512];
  __shared__ float sc[64];
  qv[tid] = qh[b * 512 + tid];
  __syncthreads();
  if (tid < 64) {
    const float* mp = mem + ((size_t)b * 64 + tid) * 512;
    float s = 0.f;
    for (int d = 0; d < 512; ++d) s += mp[d] * qv[d];
    float mx = s;
#pragma unroll
    for (int off = 32; off > 0; off >>= 1) mx = fmaxf(mx, __shfl_xor(mx, off));
    float e = expf(s - mx);
    float sum = e;
#pragma unroll
    for (int off = 32; off > 0; off >>= 1) sum += __shfl_xor(sum, off);
    sc[tid] = e / sum;
  }
  __syncthreads();
  float a = 0.f;
  for (int m = 0; m < 64; ++m) a += sc[m] * mem[((size_t)b * 64 + m) * 512 + tid];
  ctx[b * 512 + tid] = a;
  ctxT[(size_t)tid * 64 + b] = a;
}

// out[b,n] = ctx[b,:] @ out_w[:,n] + out_b[n] -- FP32 output (ref dtype)
// Rewritten for occupancy: old version ran 197 blocks (0.77 waves/SIMD,
// 9% occupancy, 270 GB/s, latency-bound at 265us). Now: batch split 4x
// (16 accs/thread) -> 788 blocks (~3 waves/SIMD); ctx read via ctxT with
// wave-uniform addresses (compiler scalarizes to s_load: no LDS, no VALU);
// the 4 blocks sharing one 256-col weight slab are placed on the SAME XCD
// (bids congruent mod 8) so each slab is HBM-fetched once.
__global__ __launch_bounds__(256) void out_gemm_k(const float* __restrict__ ctxT,
                                                  const void* __restrict__ out_w,
                                                  const void* __restrict__ out_b,
                                                  float* __restrict__ out,
                                                  const int* __restrict__ flagp) {
  int isbf = *flagp;
  int bid = blockIdx.x;
  int xslab = (bid & 7) + ((bid >> 5) << 3);   // column-slab id
  if (xslab >= 197) return;                    // 800-block launch, 788 active
  int bg = (bid >> 3) & 3;                     // batch group 0..3 (same XCD per slab)
  int n = xslab * 256 + threadIdx.x;
  int nc = n < VV ? n : VV - 1;
  int b0 = bg << 4;
  float acc[16];
#pragma unroll
  for (int i = 0; i < 16; ++i) acc[i] = 0.f;
  if (isbf) {
    const u16* wp = (const u16*)out_w;
#pragma unroll 4
    for (int k = 0; k < 512; ++k) {
      float w = bf2f(wp[(size_t)k * VV + nc]);
      const float* cp = ctxT + ((size_t)k << 6) + b0;   // uniform address
#pragma unroll
      for (int i = 0; i < 16; ++i) acc[i] += cp[i] * w;
    }
  } else {
    const float* wp = (const float*)out_w;
#pragma unroll 4
    for (int k = 0; k < 512; ++k) {
      float w = wp[(size_t)k * VV + nc];
      const float* cp = ctxT + ((size_t)k << 6) + b0;
#pragma unroll
      for (int i = 0; i < 16; ++i) acc[i] += cp[i] * w;
    }
  }
  if (n < VV) {
    float ob = ldsel(out_b, n, isbf);
#pragma unroll
    for (int i = 0; i < 16; ++i) out[(size_t)(b0 + i) * VV + n] = acc[i] + ob;
  }
}

extern "C" void kernel_launch(void* const* d_in, const int* in_sizes, int n_in,
                              void* d_out, int out_size, void* d_ws, size_t ws_size,
                              hipStream_t stream) {
  const int*  seq    = (const int*)d_in[0];
  const void* embed  = d_in[1];
  const void* ff_w1  = d_in[2];
  const void* ff_b1  = d_in[3];
  const void* ff_w2  = d_in[4];
  const void* ff_b2  = d_in[5];
  const void* ln_g   = d_in[6];
  const void* ln_b   = d_in[7];
  const void* fg_w   = d_in[8];
  const void* fg_b   = d_in[9];
  const void* nw_w1  = d_in[10];
  const void* nw_b1  = d_in[11];
  const void* nw_w2  = d_in[12];
  const void* nw_b2  = d_in[13];
  const void* wq     = d_in[14];
  const void* bq     = d_in[15];
  const void* wk     = d_in[16];
  const void* bk     = d_in[17];
  const void* wv     = d_in[18];
  const void* bv     = d_in[19];
  const void* wo     = d_in[20];
  const void* bo     = d_in[21];
  const void* rq_w   = d_in[22];
  const void* rq_b   = d_in[23];
  const void* out_w  = d_in[24];
  const void* out_b  = d_in[25];
  float* out = (float*)d_out;   // reference output dtype is float32

  // ---- workspace layout (float units), total 43,778,048 f = 175,112,192 B
  float* ws = (float*)d_ws;
  float* hidden = ws;                             // [0, 16,777,216)
  float* R      = ws + 16777216;                  // [16.78M, 33.55M): actH/g1/kkvv
  float* actH   = R;                              // 32768x512 f
  float* g1     = R;                              // 32768x512 f
  u16*   kku    = (u16*)R;                        // 32768x512 u16 (32MB)
  u16*   vvu    = (u16*)(ws + 25165824);          // 32768x512 u16 (32MB)
  size_t S0 = 33554432;
  float* fwd_scores = ws + S0;                    // 32768 (dead after topk ->
                                                  //  reused as ctxT[512][64])
  float* gs         = ws + S0 + 32768;
  float* context    = ws + S0 + 65536;
  float* gate_bias  = ws + S0 + 98304;
  float* qh         = ws + S0 + 131072;
  float* ctx        = ws + S0 + 163840;
  int*   fwd_idx    = (int*)(ws + S0 + 196608);   // 3072 i
  int*   sel        = (int*)(ws + S0 + 199680);   // 1024 i
  int*   fwd_mask   = (int*)(ws + S0 + 200704);   // 32768 i
  int*   flagp      = (int*)(ws + S0 + 233472);
  float* fwd_h      = ws + S0 + 262144;           // 1,572,864
  float* q          = ws + S0 + 1835008;
  float* Smat       = ws + S0 + 3407872;          // also: context partials
                                                  //  (512x512 f, dead before s_k)
  float* attn_out   = ws + S0 + 4980736;
  float* re_dense   = ws + S0 + 6553600;
  float* memory     = ws + S0 + 8126464;          // 2,097,152 -> end 10,223,616
  float* ctxT       = fwd_scores;                 // 512x64 f
  const size_t NEED = (size_t)(33554432 + 10223616) * 4;

  if (ws_size < NEED) {
    float val = 500.0f + (float)(ws_size >> 20);
    sentinel_k<<<(out_size + 255) / 256, 256, 0, stream>>>(out, out_size, val);
    return;
  }

  detect_k<<<1, 1, 0, stream>>>((const unsigned int*)embed, flagp);

  // FFN in two K-halves to cap scratch at 64MB:
  gemm_k<1,0,1,0,0><<<dim3(8,512),256,0,stream>>>(
      nullptr, 512, embed, seq, ff_w1, 1024, 0, ff_b1, 0,
      nullptr, nullptr, 0, nullptr, 0, 0, actH, 512, 512, flagp);
  gemm_k<0,0,0,0,0><<<dim3(8,512),256,0,stream>>>(
      actH, 512, nullptr, nullptr, ff_w2, 512, 0, nullptr, 0,
      nullptr, nullptr, 0, nullptr, 0, 0, hidden, 512, 512, flagp);
  gemm_k<1,0,1,0,0><<<dim3(8,512),256,0,stream>>>(
      nullptr, 512, embed, seq, ff_w1, 1024, 512, ff_b1, 512,
      nullptr, nullptr, 0, nullptr, 0, 0, actH, 512, 512, flagp);
  gemm_k<0,1,0,1,0><<<dim3(8,512),256,0,stream>>>(
      actH, 512, nullptr, nullptr, ff_w2, 512, (size_t)512*512, ff_b2, 0,
      embed, seq, 512, nullptr, 0, 0, hidden, 512, 512, flagp);
  // LayerNorm in place
  ln_k<<<32768,256,0,stream>>>(hidden, ln_g, ln_b, flagp);
  // forward gate scores + top-48 + mask
  score_k<0><<<dim3(8,64),256,0,stream>>>(hidden, fg_w, fg_b, fwd_scores, flagp);
  topk_fwd_k<<<64,256,0,stream>>>(fwd_scores, fwd_idx, fwd_mask);
  // context mean (two-stage; partials in Smat region, dead until s_k)
  context_part_k<<<512,512,0,stream>>>(hidden, Smat);
  context_red_k<<<64,512,0,stream>>>(Smat, context);
  // gate_bias = context @ nw_w1[512:,:] + nw_b1
  gemm_k<0,0,0,0,0><<<dim3(8,1),256,0,stream>>>(
      context, 512, nullptr, nullptr, nw_w1, 512, (size_t)512*512, nw_b1, 0,
      nullptr, nullptr, 0, nullptr, 0, 0, gate_bias, 512, 512, flagp);
  // g1 = relu(hidden @ nw_w1[:512,:] + gate_bias[b])
  gemm_k<0,2,1,0,0><<<dim3(8,512),256,0,stream>>>(
      hidden, 512, nullptr, nullptr, nw_w1, 512, 0, nullptr, 0,
      nullptr, nullptr, 0, gate_bias, 9, 512, g1, 512, 512, flagp);
  // gs = sigmoid(g1 @ nw_w2 + nw_b2)
  score_k<1><<<dim3(8,64),256,0,stream>>>(g1, nw_w2, nw_b2, gs, flagp);
  // retro top-16 + gather into memory[48:64]
  topk_retro_k<<<64,256,0,stream>>>(gs, fwd_mask, sel);
  retro_gather_k<<<2048,256,0,stream>>>(hidden, sel, memory);
  // fwd_h gather, q projection
  fwdh_gather_k<<<6144,256,0,stream>>>(hidden, fwd_idx, fwd_h);
  gemm_k<0,0,0,0,0><<<dim3(8,48),256,0,stream>>>(
      fwd_h, 512, nullptr, nullptr, wq, 512, 0, bq, 0,
      nullptr, nullptr, 0, nullptr, 0, 0, q, 512, 512, flagp);
  // K,V projections (bf16 out; g1 dead now, region reused)
  gemm_k<0,0,0,0,1><<<dim3(8,512),256,0,stream>>>(
      hidden, 512, nullptr, nullptr, wk, 512, 0, bk, 0,
      nullptr, nullptr, 0, nullptr, 0, 0, kku, 512, 512, flagp);
  gemm_k<0,0,0,0,1><<<dim3(8,512),256,0,stream>>>(
      hidden, 512, nullptr, nullptr, wv, 512, 0, bv, 0,
      nullptr, nullptr, 0, nullptr, 0, 0, vvu, 512, 512, flagp);
  // attention
  s_k<<<dim3(8,64),256,0,stream>>>(q, kku, Smat);
  softmax_k<<<3072,256,0,stream>>>(Smat);
  pv_k<<<dim3(8,64),256,0,stream>>>(Smat, vvu, attn_out);
  // re_slots = attn_out @ wo + bo -> memory[0:48]
  gemm_k<0,0,0,0,0><<<dim3(8,48),256,0,stream>>>(
      attn_out, 512, nullptr, nullptr, wo, 512, 0, bo, 0,
      nullptr, nullptr, 0, nullptr, 0, 0, re_dense, 512, 512, flagp);
  copy_re_k<<<6144,256,0,stream>>>(re_dense, memory);
  // qh, memory softmax (also emits ctxT), vocab projection
  qh_k<<<64,512,0,stream>>>(hidden, rq_w, rq_b, qh, flagp);
  mem_attn_k<<<64,512,0,stream>>>(memory, qh, ctx, ctxT);
  out_gemm_k<<<800,256,0,stream>>>(ctxT, out_w, out_b, out, flagp);
}